// Round 1
// baseline (7111.532 us; speedup 1.0000x reference)
//
#include <hip/hip_runtime.h>
#include <cstdint>
#include <cstddef>

#define N_NODES_C 200000
#define N_EDGES_C 600000
#define NUM_GRAPHS_C 20000

constexpr float NEG_SLOPE = 0.2f;
constexpr float LN_EPS = 1e-5f;

// ---------------- CSR build ----------------

__global__ __launch_bounds__(256) void count_deg_kernel(const int* __restrict__ dst,
                                                        int* __restrict__ deg, int E) {
  int e = blockIdx.x * 256 + threadIdx.x;
  if (e < E) atomicAdd(&deg[dst[e]], 1);
}

// exclusive scan, 1024 elements per block (256 threads x 4)
__global__ __launch_bounds__(256) void scan_kernel(const int* __restrict__ in,
                                                   int* __restrict__ out,
                                                   int* __restrict__ bsums, int n) {
  __shared__ int ss[256];
  int t = threadIdx.x;
  int base = blockIdx.x * 1024 + t * 4;
  int v[4];
  int s = 0;
#pragma unroll
  for (int j = 0; j < 4; ++j) {
    v[j] = (base + j < n) ? in[base + j] : 0;
    s += v[j];
  }
  ss[t] = s;
  __syncthreads();
  for (int off = 1; off < 256; off <<= 1) {
    int x = (t >= off) ? ss[t - off] : 0;
    __syncthreads();
    ss[t] += x;
    __syncthreads();
  }
  int incl = ss[t];
  int excl = incl - s;
  if (bsums != nullptr && t == 255) bsums[blockIdx.x] = incl;
  int run = excl;
#pragma unroll
  for (int j = 0; j < 4; ++j) {
    if (base + j < n) out[base + j] = run;
    run += v[j];
  }
}

__global__ __launch_bounds__(256) void scan_addoff_kernel(int* __restrict__ data,
                                                          const int* __restrict__ boff,
                                                          int n, int total) {
  int base = blockIdx.x * 1024 + threadIdx.x * 4;
  int add = boff[blockIdx.x];
#pragma unroll
  for (int j = 0; j < 4; ++j) {
    if (base + j < n) data[base + j] += add;
  }
  if (blockIdx.x == 0 && threadIdx.x == 0) data[n] = total;
}

__global__ __launch_bounds__(256) void fill_csr_kernel(const int* __restrict__ src,
                                                       const int* __restrict__ dst,
                                                       const int* __restrict__ row_ptr,
                                                       int* __restrict__ cursor,
                                                       int* __restrict__ col, int E) {
  int e = blockIdx.x * 256 + threadIdx.x;
  if (e < E) {
    int d = dst[e];
    int p = atomicAdd(&cursor[d], 1);
    col[row_ptr[d] + p] = src[e];
  }
}

// ---------------- GEMM: C[M,128] = A[M,128] @ W[128,128], fp32 ----------------

__global__ __launch_bounds__(256) void gemm_nk128(const float* __restrict__ A,
                                                  const float* __restrict__ W,
                                                  float* __restrict__ C, int M) {
  __shared__ float As[64][32];
  __shared__ float Ws[32][128];
  int tid = threadIdx.x;
  int tx = tid & 31;   // col group (4 cols)
  int ty = tid >> 5;   // 0..7
  int row0 = blockIdx.x * 64;
  float4 acc[8];
#pragma unroll
  for (int r = 0; r < 8; ++r) acc[r] = make_float4(0.f, 0.f, 0.f, 0.f);

  for (int k0 = 0; k0 < 128; k0 += 32) {
    // A tile: 64 rows x 32 k  (512 float4)
#pragma unroll
    for (int i = 0; i < 2; ++i) {
      int idx = tid + i * 256;
      int r = idx >> 3;
      int c4 = idx & 7;
      int gr = row0 + r;
      float4 v = make_float4(0.f, 0.f, 0.f, 0.f);
      if (gr < M) v = *(const float4*)(A + (size_t)gr * 128 + k0 + c4 * 4);
      *(float4*)&As[r][c4 * 4] = v;
    }
    // W tile: 32 k x 128 cols (1024 float4)
#pragma unroll
    for (int i = 0; i < 4; ++i) {
      int idx = tid + i * 256;
      int r = idx >> 5;
      int c4 = idx & 31;
      *(float4*)&Ws[r][c4 * 4] = *(const float4*)(W + (size_t)(k0 + r) * 128 + c4 * 4);
    }
    __syncthreads();
    for (int kk = 0; kk < 32; ++kk) {
      float4 w = *(const float4*)&Ws[kk][tx * 4];
#pragma unroll
      for (int r = 0; r < 8; ++r) {
        float a = As[ty + r * 8][kk];
        acc[r].x = fmaf(a, w.x, acc[r].x);
        acc[r].y = fmaf(a, w.y, acc[r].y);
        acc[r].z = fmaf(a, w.z, acc[r].z);
        acc[r].w = fmaf(a, w.w, acc[r].w);
      }
    }
    __syncthreads();
  }
#pragma unroll
  for (int r = 0; r < 8; ++r) {
    int gr = row0 + ty + r * 8;
    if (gr < M) *(float4*)(C + (size_t)gr * 128 + tx * 4) = acc[r];
  }
}

// ---------------- attention scores: a = <h_row_headslice, att_headslice> ----------------

template <int H>
__global__ __launch_bounds__(256) void att_scores_kernel(const float* __restrict__ h,
                                                         const float* __restrict__ att_src,
                                                         const float* __restrict__ att_dst,
                                                         float* __restrict__ asrc,
                                                         float* __restrict__ adst, int n) {
  int wid = (blockIdx.x * 256 + threadIdx.x) >> 6;
  int lane = threadIdx.x & 63;
  if (wid >= n) return;
  int c0 = lane * 2;
  float2 hv = *(const float2*)(h + (size_t)wid * 128 + c0);
  float2 vs = *(const float2*)(att_src + c0);
  float2 vd = *(const float2*)(att_dst + c0);
  float ps = hv.x * vs.x + hv.y * vs.y;
  float pd = hv.x * vd.x + hv.y * vd.y;
  constexpr int SEG = 64 / H;  // lanes per head
#pragma unroll
  for (int off = 1; off < SEG; off <<= 1) {
    ps += __shfl_xor(ps, off, 64);
    pd += __shfl_xor(pd, off, 64);
  }
  if ((lane & (SEG - 1)) == 0) {
    int hd = lane / SEG;
    asrc[(size_t)wid * H + hd] = ps;
    adst[(size_t)wid * H + hd] = pd;
  }
}

// ---------------- GAT aggregation (wave per node, 3 passes, implicit self loop) -----

template <int H, bool RELU, bool LNPOOL>
__global__ __launch_bounds__(256) void gat_agg_kernel(
    const float* __restrict__ h, const float* __restrict__ asrc,
    const float* __restrict__ adst, const int* __restrict__ row_ptr,
    const int* __restrict__ col, const float* __restrict__ bias,
    const float* __restrict__ gamma, const float* __restrict__ beta,
    const int* __restrict__ batch, float* __restrict__ out, float* __restrict__ cnt,
    int n) {
  int node = (blockIdx.x * 256 + threadIdx.x) >> 6;
  int lane = threadIdx.x & 63;
  if (node >= n) return;
  int e0 = row_ptr[node];
  int e1 = row_ptr[node + 1];  // index e1 == implicit self loop

  float ad[H], m[H], denom[H];
#pragma unroll
  for (int hh = 0; hh < H; ++hh) {
    ad[hh] = adst[(size_t)node * H + hh];
    m[hh] = -1e30f;
    denom[hh] = 0.f;
  }
  // pass 1: per-head max of leaky_relu(asrc[s]+adst[node])
  for (int e = e0; e <= e1; ++e) {
    int s = (e < e1) ? col[e] : node;
#pragma unroll
    for (int hh = 0; hh < H; ++hh) {
      float a = asrc[(size_t)s * H + hh] + ad[hh];
      a = (a > 0.f) ? a : NEG_SLOPE * a;
      m[hh] = fmaxf(m[hh], a);
    }
  }
  // pass 2: denom
  for (int e = e0; e <= e1; ++e) {
    int s = (e < e1) ? col[e] : node;
#pragma unroll
    for (int hh = 0; hh < H; ++hh) {
      float a = asrc[(size_t)s * H + hh] + ad[hh];
      a = (a > 0.f) ? a : NEG_SLOPE * a;
      denom[hh] += expf(a - m[hh]);
    }
  }
  // pass 3: aggregate h[src] * coef
  int c0 = lane * 2;
  const int hd = (H == 1) ? 0 : (c0 / (128 / H));
  float2 acc = make_float2(0.f, 0.f);
  for (int e = e0; e <= e1; ++e) {
    int s = (e < e1) ? col[e] : node;
    float a = asrc[(size_t)s * H + hd] + ad[hd];
    a = (a > 0.f) ? a : NEG_SLOPE * a;
    float coef = expf(a - m[hd]) / denom[hd];
    float2 hv = *(const float2*)(h + (size_t)s * 128 + c0);
    acc.x = fmaf(hv.x, coef, acc.x);
    acc.y = fmaf(hv.y, coef, acc.y);
  }
  acc.x += bias[c0];
  acc.y += bias[c0 + 1];
  if (RELU) {
    acc.x = fmaxf(acc.x, 0.f);
    acc.y = fmaxf(acc.y, 0.f);
  }
  if (!LNPOOL) {
    *(float2*)(out + (size_t)node * 128 + c0) = acc;
  } else {
    // LayerNorm across 128 channels held by the wave (2/lane)
    float ssum = acc.x + acc.y;
#pragma unroll
    for (int off = 1; off < 64; off <<= 1) ssum += __shfl_xor(ssum, off, 64);
    float mu = ssum * (1.f / 128.f);
    float dx = acc.x - mu, dy = acc.y - mu;
    float vs2 = dx * dx + dy * dy;
#pragma unroll
    for (int off = 1; off < 64; off <<= 1) vs2 += __shfl_xor(vs2, off, 64);
    float inv = rsqrtf(vs2 * (1.f / 128.f) + LN_EPS);
    float ox = dx * inv * gamma[c0] + beta[c0];
    float oy = dy * inv * gamma[c0 + 1] + beta[c0 + 1];
    int g = batch[node];
    atomicAdd(&out[(size_t)g * 128 + c0], ox);
    atomicAdd(&out[(size_t)g * 128 + c0 + 1], oy);
    if (lane == 0) atomicAdd(&cnt[g], 1.0f);
  }
}

__global__ __launch_bounds__(256) void pool_div_kernel(float* __restrict__ out,
                                                       const float* __restrict__ cnt,
                                                       int total) {
  int i = blockIdx.x * 256 + threadIdx.x;
  if (i < total) out[i] = out[i] / fmaxf(cnt[i >> 7], 1.0f);
}

// ---------------- launch ----------------

extern "C" void kernel_launch(void* const* d_in, const int* in_sizes, int n_in,
                              void* d_out, int out_size, void* d_ws, size_t ws_size,
                              hipStream_t stream) {
  const float* x = (const float*)d_in[0];
  const int* ei = (const int*)d_in[1];
  const int* batch = (const int*)d_in[2];
  const float* W1 = (const float*)d_in[3];
  const float* att_src1 = (const float*)d_in[4];
  const float* att_dst1 = (const float*)d_in[5];
  const float* b1 = (const float*)d_in[6];
  const float* W2 = (const float*)d_in[7];
  const float* att_src2 = (const float*)d_in[8];
  const float* att_dst2 = (const float*)d_in[9];
  const float* b2 = (const float*)d_in[10];
  const float* gamma = (const float*)d_in[11];
  const float* beta = (const float*)d_in[12];
  float* out = (float*)d_out;

  const int N = N_NODES_C, E = N_EDGES_C, G = NUM_GRAPHS_C;
  const int* src = ei;
  const int* dst = ei + E;

  float* p = (float*)d_ws;
  float* h_a = p;   p += (size_t)N * 128;   // h1_pre, later h2_pre
  float* h_b = p;   p += (size_t)N * 128;   // h1 (post relu)
  float* asrc1 = p; p += (size_t)N * 4;
  float* adst1 = p; p += (size_t)N * 4;
  float* asrc2 = p; p += N;
  float* adst2 = p; p += N;
  float* cnt = p;   p += G;
  int* ip = (int*)p;
  int* deg = ip;     ip += N;
  int* cursor = ip;  ip += N;
  int* col = ip;     ip += E;
  int* bsums = ip;   ip += 256;
  int* bsums2 = ip;  ip += 256;
  int* row_ptr = ip; ip += N + 1;
  (void)ws_size; (void)in_sizes; (void)n_in; (void)out_size;

  hipMemsetAsync(deg, 0, sizeof(int) * (size_t)N, stream);
  hipMemsetAsync(cursor, 0, sizeof(int) * (size_t)N, stream);
  hipMemsetAsync(cnt, 0, sizeof(float) * (size_t)G, stream);
  hipMemsetAsync(d_out, 0, sizeof(float) * (size_t)G * 128, stream);

  // CSR by destination
  count_deg_kernel<<<(E + 255) / 256, 256, 0, stream>>>(dst, deg, E);
  int nblk = (N + 1023) / 1024;
  scan_kernel<<<nblk, 256, 0, stream>>>(deg, row_ptr, bsums, N);
  scan_kernel<<<1, 256, 0, stream>>>(bsums, bsums2, nullptr, nblk);
  scan_addoff_kernel<<<nblk, 256, 0, stream>>>(row_ptr, bsums2, N, E);
  fill_csr_kernel<<<(E + 255) / 256, 256, 0, stream>>>(src, dst, row_ptr, cursor, col, E);

  int wblocks = (int)(((size_t)N * 64 + 255) / 256);  // wave per node

  // Layer 1: GAT(128 -> 4x32), ReLU
  gemm_nk128<<<(N + 63) / 64, 256, 0, stream>>>(x, W1, h_a, N);
  att_scores_kernel<4><<<wblocks, 256, 0, stream>>>(h_a, att_src1, att_dst1, asrc1, adst1, N);
  gat_agg_kernel<4, true, false><<<wblocks, 256, 0, stream>>>(
      h_a, asrc1, adst1, row_ptr, col, b1, nullptr, nullptr, nullptr, h_b, nullptr, N);

  // Layer 2: GAT(128 -> 1x128) + LayerNorm + mean-pool (fused into epilogue)
  gemm_nk128<<<(N + 63) / 64, 256, 0, stream>>>(h_b, W2, h_a, N);
  att_scores_kernel<1><<<wblocks, 256, 0, stream>>>(h_a, att_src2, att_dst2, asrc2, adst2, N);
  gat_agg_kernel<1, false, true><<<wblocks, 256, 0, stream>>>(
      h_a, asrc2, adst2, row_ptr, col, b2, gamma, beta, batch, out, cnt, N);

  pool_div_kernel<<<(G * 128 + 255) / 256, 256, 0, stream>>>(out, cnt, G * 128);
}

// Round 2
// 905.013 us; speedup vs baseline: 7.8579x; 7.8579x over previous
//
#include <hip/hip_runtime.h>
#include <cstdint>
#include <cstddef>

#define N_NODES_C 200000
#define N_EDGES_C 600000
#define NUM_GRAPHS_C 20000

constexpr float NEG_SLOPE = 0.2f;
constexpr float LN_EPS = 1e-5f;

// ---------------- CSR build ----------------

__global__ __launch_bounds__(256) void count_deg_kernel(const int* __restrict__ dst,
                                                        int* __restrict__ deg, int E) {
  int e = blockIdx.x * 256 + threadIdx.x;
  if (e < E) atomicAdd(&deg[dst[e]], 1);
}

// exclusive scan, 1024 elements per block (256 threads x 4)
__global__ __launch_bounds__(256) void scan_kernel(const int* __restrict__ in,
                                                   int* __restrict__ out,
                                                   int* __restrict__ bsums, int n) {
  __shared__ int ss[256];
  int t = threadIdx.x;
  int base = blockIdx.x * 1024 + t * 4;
  int v[4];
  int s = 0;
#pragma unroll
  for (int j = 0; j < 4; ++j) {
    v[j] = (base + j < n) ? in[base + j] : 0;
    s += v[j];
  }
  ss[t] = s;
  __syncthreads();
  for (int off = 1; off < 256; off <<= 1) {
    int x = (t >= off) ? ss[t - off] : 0;
    __syncthreads();
    ss[t] += x;
    __syncthreads();
  }
  int incl = ss[t];
  int excl = incl - s;
  if (bsums != nullptr && t == 255) bsums[blockIdx.x] = incl;
  int run = excl;
#pragma unroll
  for (int j = 0; j < 4; ++j) {
    if (base + j < n) out[base + j] = run;
    run += v[j];
  }
}

__global__ __launch_bounds__(256) void scan_addoff_kernel(int* __restrict__ data,
                                                          const int* __restrict__ boff,
                                                          int n, int total) {
  int base = blockIdx.x * 1024 + threadIdx.x * 4;
  int add = boff[blockIdx.x];
#pragma unroll
  for (int j = 0; j < 4; ++j) {
    if (base + j < n) data[base + j] += add;
  }
  if (blockIdx.x == 0 && threadIdx.x == 0) data[n] = total;
}

__global__ __launch_bounds__(256) void fill_csr_kernel(const int* __restrict__ src,
                                                       const int* __restrict__ dst,
                                                       const int* __restrict__ row_ptr,
                                                       int* __restrict__ cursor,
                                                       int* __restrict__ col, int E) {
  int e = blockIdx.x * 256 + threadIdx.x;
  if (e < E) {
    int d = dst[e];
    int p = atomicAdd(&cursor[d], 1);
    col[row_ptr[d] + p] = src[e];
  }
}

// ---------------- GEMM: C[M,128] = A[M,128] @ W[128,128], fp32 ----------------
// 32x128 block tile, 4 rows x 4 cols per thread (16 acc regs), K staged in
// 32-wide LDS tiles. Outer K loop pinned (#pragma unroll 1) so live set stays
// small -> no scratch spill (round-1 failure mode: 256 VGPR + 7.5GB spill).

__global__ __launch_bounds__(256) void gemm_nk128(const float* __restrict__ A,
                                                  const float* __restrict__ W,
                                                  float* __restrict__ C, int M) {
  __shared__ float As[32][32];
  __shared__ float Ws[32][128];
  int tid = threadIdx.x;
  int tx = tid & 31;   // col group (4 cols)
  int ty = tid >> 5;   // 0..7
  int row0 = blockIdx.x * 32;
  float4 acc[4];
#pragma unroll
  for (int r = 0; r < 4; ++r) acc[r] = make_float4(0.f, 0.f, 0.f, 0.f);

#pragma unroll 1
  for (int k0 = 0; k0 < 128; k0 += 32) {
    // A tile: 32 rows x 32 k (256 float4, one per thread)
    {
      int r = tid >> 3;
      int c4 = tid & 7;
      int gr = row0 + r;
      float4 v = make_float4(0.f, 0.f, 0.f, 0.f);
      if (gr < M) v = *(const float4*)(A + (size_t)gr * 128 + k0 + c4 * 4);
      *(float4*)&As[r][c4 * 4] = v;
    }
    // W tile: 32 k x 128 cols (1024 float4)
#pragma unroll
    for (int i = 0; i < 4; ++i) {
      int idx = tid + i * 256;
      int r = idx >> 5;
      int c4 = idx & 31;
      *(float4*)&Ws[r][c4 * 4] = *(const float4*)(W + (size_t)(k0 + r) * 128 + c4 * 4);
    }
    __syncthreads();
#pragma unroll
    for (int kk = 0; kk < 32; ++kk) {
      float4 w = *(const float4*)&Ws[kk][tx * 4];
#pragma unroll
      for (int r = 0; r < 4; ++r) {
        float a = As[ty + r * 8][kk];
        acc[r].x = fmaf(a, w.x, acc[r].x);
        acc[r].y = fmaf(a, w.y, acc[r].y);
        acc[r].z = fmaf(a, w.z, acc[r].z);
        acc[r].w = fmaf(a, w.w, acc[r].w);
      }
    }
    __syncthreads();
  }
#pragma unroll
  for (int r = 0; r < 4; ++r) {
    int gr = row0 + ty + r * 8;
    if (gr < M) *(float4*)(C + (size_t)gr * 128 + tx * 4) = acc[r];
  }
}

// ---------------- attention scores: a = <h_row_headslice, att_headslice> ----------------

template <int H>
__global__ __launch_bounds__(256) void att_scores_kernel(const float* __restrict__ h,
                                                         const float* __restrict__ att_src,
                                                         const float* __restrict__ att_dst,
                                                         float* __restrict__ asrc,
                                                         float* __restrict__ adst, int n) {
  int wid = (blockIdx.x * 256 + threadIdx.x) >> 6;
  int lane = threadIdx.x & 63;
  if (wid >= n) return;
  int c0 = lane * 2;
  float2 hv = *(const float2*)(h + (size_t)wid * 128 + c0);
  float2 vs = *(const float2*)(att_src + c0);
  float2 vd = *(const float2*)(att_dst + c0);
  float ps = hv.x * vs.x + hv.y * vs.y;
  float pd = hv.x * vd.x + hv.y * vd.y;
  constexpr int SEG = 64 / H;  // lanes per head
#pragma unroll
  for (int off = 1; off < SEG; off <<= 1) {
    ps += __shfl_xor(ps, off, 64);
    pd += __shfl_xor(pd, off, 64);
  }
  if ((lane & (SEG - 1)) == 0) {
    int hd = lane / SEG;
    asrc[(size_t)wid * H + hd] = ps;
    adst[(size_t)wid * H + hd] = pd;
  }
}

// ---------------- GAT aggregation (wave per node, 3 passes, implicit self loop) -----

template <int H, bool RELU, bool LNPOOL>
__global__ __launch_bounds__(256) void gat_agg_kernel(
    const float* __restrict__ h, const float* __restrict__ asrc,
    const float* __restrict__ adst, const int* __restrict__ row_ptr,
    const int* __restrict__ col, const float* __restrict__ bias,
    const float* __restrict__ gamma, const float* __restrict__ beta,
    const int* __restrict__ batch, float* __restrict__ out, float* __restrict__ cnt,
    int n) {
  int node = (blockIdx.x * 256 + threadIdx.x) >> 6;
  int lane = threadIdx.x & 63;
  if (node >= n) return;
  int e0 = row_ptr[node];
  int e1 = row_ptr[node + 1];  // index e1 == implicit self loop

  float ad[H], m[H], denom[H];
#pragma unroll
  for (int hh = 0; hh < H; ++hh) {
    ad[hh] = adst[(size_t)node * H + hh];
    m[hh] = -1e30f;
    denom[hh] = 0.f;
  }
  // pass 1: per-head max of leaky_relu(asrc[s]+adst[node])
  for (int e = e0; e <= e1; ++e) {
    int s = (e < e1) ? col[e] : node;
#pragma unroll
    for (int hh = 0; hh < H; ++hh) {
      float a = asrc[(size_t)s * H + hh] + ad[hh];
      a = (a > 0.f) ? a : NEG_SLOPE * a;
      m[hh] = fmaxf(m[hh], a);
    }
  }
  // pass 2: denom
  for (int e = e0; e <= e1; ++e) {
    int s = (e < e1) ? col[e] : node;
#pragma unroll
    for (int hh = 0; hh < H; ++hh) {
      float a = asrc[(size_t)s * H + hh] + ad[hh];
      a = (a > 0.f) ? a : NEG_SLOPE * a;
      denom[hh] += expf(a - m[hh]);
    }
  }
  // pass 3: aggregate h[src] * coef
  int c0 = lane * 2;
  const int hd = (H == 1) ? 0 : (c0 / (128 / H));
  float2 acc = make_float2(0.f, 0.f);
  for (int e = e0; e <= e1; ++e) {
    int s = (e < e1) ? col[e] : node;
    float a = asrc[(size_t)s * H + hd] + ad[hd];
    a = (a > 0.f) ? a : NEG_SLOPE * a;
    float coef = expf(a - m[hd]) / denom[hd];
    float2 hv = *(const float2*)(h + (size_t)s * 128 + c0);
    acc.x = fmaf(hv.x, coef, acc.x);
    acc.y = fmaf(hv.y, coef, acc.y);
  }
  acc.x += bias[c0];
  acc.y += bias[c0 + 1];
  if (RELU) {
    acc.x = fmaxf(acc.x, 0.f);
    acc.y = fmaxf(acc.y, 0.f);
  }
  if (!LNPOOL) {
    *(float2*)(out + (size_t)node * 128 + c0) = acc;
  } else {
    // LayerNorm across 128 channels held by the wave (2/lane)
    float ssum = acc.x + acc.y;
#pragma unroll
    for (int off = 1; off < 64; off <<= 1) ssum += __shfl_xor(ssum, off, 64);
    float mu = ssum * (1.f / 128.f);
    float dx = acc.x - mu, dy = acc.y - mu;
    float vs2 = dx * dx + dy * dy;
#pragma unroll
    for (int off = 1; off < 64; off <<= 1) vs2 += __shfl_xor(vs2, off, 64);
    float inv = rsqrtf(vs2 * (1.f / 128.f) + LN_EPS);
    float ox = dx * inv * gamma[c0] + beta[c0];
    float oy = dy * inv * gamma[c0 + 1] + beta[c0 + 1];
    int g = batch[node];
    atomicAdd(&out[(size_t)g * 128 + c0], ox);
    atomicAdd(&out[(size_t)g * 128 + c0 + 1], oy);
    if (lane == 0) atomicAdd(&cnt[g], 1.0f);
  }
}

__global__ __launch_bounds__(256) void pool_div_kernel(float* __restrict__ out,
                                                       const float* __restrict__ cnt,
                                                       int total) {
  int i = blockIdx.x * 256 + threadIdx.x;
  if (i < total) out[i] = out[i] / fmaxf(cnt[i >> 7], 1.0f);
}

// ---------------- launch ----------------

extern "C" void kernel_launch(void* const* d_in, const int* in_sizes, int n_in,
                              void* d_out, int out_size, void* d_ws, size_t ws_size,
                              hipStream_t stream) {
  const float* x = (const float*)d_in[0];
  const int* ei = (const int*)d_in[1];
  const int* batch = (const int*)d_in[2];
  const float* W1 = (const float*)d_in[3];
  const float* att_src1 = (const float*)d_in[4];
  const float* att_dst1 = (const float*)d_in[5];
  const float* b1 = (const float*)d_in[6];
  const float* W2 = (const float*)d_in[7];
  const float* att_src2 = (const float*)d_in[8];
  const float* att_dst2 = (const float*)d_in[9];
  const float* b2 = (const float*)d_in[10];
  const float* gamma = (const float*)d_in[11];
  const float* beta = (const float*)d_in[12];
  float* out = (float*)d_out;

  const int N = N_NODES_C, E = N_EDGES_C, G = NUM_GRAPHS_C;
  const int* src = ei;
  const int* dst = ei + E;

  float* p = (float*)d_ws;
  float* h_a = p;   p += (size_t)N * 128;   // h1_pre, later h2_pre
  float* h_b = p;   p += (size_t)N * 128;   // h1 (post relu)
  float* asrc1 = p; p += (size_t)N * 4;
  float* adst1 = p; p += (size_t)N * 4;
  float* asrc2 = p; p += N;
  float* adst2 = p; p += N;
  float* cnt = p;   p += G;
  int* ip = (int*)p;
  int* deg = ip;     ip += N;
  int* cursor = ip;  ip += N;
  int* col = ip;     ip += E;
  int* bsums = ip;   ip += 256;
  int* bsums2 = ip;  ip += 256;
  int* row_ptr = ip; ip += N + 1;
  (void)ws_size; (void)in_sizes; (void)n_in; (void)out_size;

  hipMemsetAsync(deg, 0, sizeof(int) * (size_t)N, stream);
  hipMemsetAsync(cursor, 0, sizeof(int) * (size_t)N, stream);
  hipMemsetAsync(cnt, 0, sizeof(float) * (size_t)G, stream);
  hipMemsetAsync(d_out, 0, sizeof(float) * (size_t)G * 128, stream);

  // CSR by destination
  count_deg_kernel<<<(E + 255) / 256, 256, 0, stream>>>(dst, deg, E);
  int nblk = (N + 1023) / 1024;
  scan_kernel<<<nblk, 256, 0, stream>>>(deg, row_ptr, bsums, N);
  scan_kernel<<<1, 256, 0, stream>>>(bsums, bsums2, nullptr, nblk);
  scan_addoff_kernel<<<nblk, 256, 0, stream>>>(row_ptr, bsums2, N, E);
  fill_csr_kernel<<<(E + 255) / 256, 256, 0, stream>>>(src, dst, row_ptr, cursor, col, E);

  int wblocks = (int)(((size_t)N * 64 + 255) / 256);  // wave per node

  // Layer 1: GAT(128 -> 4x32), ReLU
  gemm_nk128<<<(N + 31) / 32, 256, 0, stream>>>(x, W1, h_a, N);
  att_scores_kernel<4><<<wblocks, 256, 0, stream>>>(h_a, att_src1, att_dst1, asrc1, adst1, N);
  gat_agg_kernel<4, true, false><<<wblocks, 256, 0, stream>>>(
      h_a, asrc1, adst1, row_ptr, col, b1, nullptr, nullptr, nullptr, h_b, nullptr, N);

  // Layer 2: GAT(128 -> 1x128) + LayerNorm + mean-pool (fused into epilogue)
  gemm_nk128<<<(N + 31) / 32, 256, 0, stream>>>(h_b, W2, h_a, N);
  att_scores_kernel<1><<<wblocks, 256, 0, stream>>>(h_a, att_src2, att_dst2, asrc2, adst2, N);
  gat_agg_kernel<1, false, true><<<wblocks, 256, 0, stream>>>(
      h_a, asrc2, adst2, row_ptr, col, b2, gamma, beta, batch, out, cnt, N);

  pool_div_kernel<<<(G * 128 + 255) / 256, 256, 0, stream>>>(out, cnt, G * 128);
}

// Round 3
// 667.305 us; speedup vs baseline: 10.6571x; 1.3562x over previous
//
#include <hip/hip_runtime.h>
#include <cstdint>
#include <cstddef>

#define N_NODES_C 200000
#define N_EDGES_C 600000
#define NUM_GRAPHS_C 20000

constexpr float NEG_SLOPE = 0.2f;
constexpr float LN_EPS = 1e-5f;

// ---------------- CSR build ----------------

__global__ __launch_bounds__(256) void count_deg_kernel(const int* __restrict__ dst,
                                                        int* __restrict__ deg, int E) {
  int e = blockIdx.x * 256 + threadIdx.x;
  if (e < E) atomicAdd(&deg[dst[e]], 1);
}

// exclusive scan, 1024 elements per block (256 threads x 4)
__global__ __launch_bounds__(256) void scan_kernel(const int* __restrict__ in,
                                                   int* __restrict__ out,
                                                   int* __restrict__ bsums, int n) {
  __shared__ int ss[256];
  int t = threadIdx.x;
  int base = blockIdx.x * 1024 + t * 4;
  int v[4];
  int s = 0;
#pragma unroll
  for (int j = 0; j < 4; ++j) {
    v[j] = (base + j < n) ? in[base + j] : 0;
    s += v[j];
  }
  ss[t] = s;
  __syncthreads();
  for (int off = 1; off < 256; off <<= 1) {
    int x = (t >= off) ? ss[t - off] : 0;
    __syncthreads();
    ss[t] += x;
    __syncthreads();
  }
  int incl = ss[t];
  int excl = incl - s;
  if (bsums != nullptr && t == 255) bsums[blockIdx.x] = incl;
  int run = excl;
#pragma unroll
  for (int j = 0; j < 4; ++j) {
    if (base + j < n) out[base + j] = run;
    run += v[j];
  }
}

__global__ __launch_bounds__(256) void scan_addoff_kernel(int* __restrict__ data,
                                                          const int* __restrict__ boff,
                                                          int n, int total) {
  int base = blockIdx.x * 1024 + threadIdx.x * 4;
  int add = boff[blockIdx.x];
#pragma unroll
  for (int j = 0; j < 4; ++j) {
    if (base + j < n) data[base + j] += add;
  }
  if (blockIdx.x == 0 && threadIdx.x == 0) data[n] = total;
}

__global__ __launch_bounds__(256) void fill_csr_kernel(const int* __restrict__ src,
                                                       const int* __restrict__ dst,
                                                       const int* __restrict__ row_ptr,
                                                       int* __restrict__ cursor,
                                                       int* __restrict__ col, int E) {
  int e = blockIdx.x * 256 + threadIdx.x;
  if (e < E) {
    int d = dst[e];
    int p = atomicAdd(&cursor[d], 1);
    col[row_ptr[d] + p] = src[e];
  }
}

// ---------------- GEMM + att-score epilogue ----------------
// C[M,128] = A[M,128] @ W[128,128]; also asrc[r,h] = <C row slice, att_src>,
// adst likewise, computed from acc registers (saves re-reading C: 2x102MB).
// 32x128 block tile, 4 rows x 4 cols/thread, outer K loop pinned (no spill).

template <int H>
__global__ __launch_bounds__(256) void gemm_att(const float* __restrict__ A,
                                                const float* __restrict__ W,
                                                const float* __restrict__ att_src,
                                                const float* __restrict__ att_dst,
                                                float* __restrict__ C,
                                                float* __restrict__ asrc,
                                                float* __restrict__ adst, int M) {
  __shared__ float As[32][32];
  __shared__ float Ws[32][128];
  int tid = threadIdx.x;
  int tx = tid & 31;   // col group (4 cols)
  int ty = tid >> 5;   // 0..7
  int row0 = blockIdx.x * 32;
  float4 acc[4];
#pragma unroll
  for (int r = 0; r < 4; ++r) acc[r] = make_float4(0.f, 0.f, 0.f, 0.f);

#pragma unroll 1
  for (int k0 = 0; k0 < 128; k0 += 32) {
    {
      int r = tid >> 3;
      int c4 = tid & 7;
      int gr = row0 + r;
      float4 v = make_float4(0.f, 0.f, 0.f, 0.f);
      if (gr < M) v = *(const float4*)(A + (size_t)gr * 128 + k0 + c4 * 4);
      *(float4*)&As[r][c4 * 4] = v;
    }
#pragma unroll
    for (int i = 0; i < 4; ++i) {
      int idx = tid + i * 256;
      int r = idx >> 5;
      int c4 = idx & 31;
      *(float4*)&Ws[r][c4 * 4] = *(const float4*)(W + (size_t)(k0 + r) * 128 + c4 * 4);
    }
    __syncthreads();
#pragma unroll
    for (int kk = 0; kk < 32; ++kk) {
      float4 w = *(const float4*)&Ws[kk][tx * 4];
#pragma unroll
      for (int r = 0; r < 4; ++r) {
        float a = As[ty + r * 8][kk];
        acc[r].x = fmaf(a, w.x, acc[r].x);
        acc[r].y = fmaf(a, w.y, acc[r].y);
        acc[r].z = fmaf(a, w.z, acc[r].z);
        acc[r].w = fmaf(a, w.w, acc[r].w);
      }
    }
    __syncthreads();
  }

  float4 vs = *(const float4*)(att_src + tx * 4);
  float4 vd = *(const float4*)(att_dst + tx * 4);
  constexpr int GRP = 32 / H;  // lanes per head within the 32-col group
#pragma unroll
  for (int r = 0; r < 4; ++r) {
    int gr = row0 + ty + r * 8;
    if (gr < M) *(float4*)(C + (size_t)gr * 128 + tx * 4) = acc[r];
    float ps = acc[r].x * vs.x + acc[r].y * vs.y + acc[r].z * vs.z + acc[r].w * vs.w;
    float pd = acc[r].x * vd.x + acc[r].y * vd.y + acc[r].z * vd.z + acc[r].w * vd.w;
#pragma unroll
    for (int off = 1; off < GRP; off <<= 1) {
      ps += __shfl_xor(ps, off, 64);
      pd += __shfl_xor(pd, off, 64);
    }
    if ((tx & (GRP - 1)) == 0 && gr < M) {
      int hd = tx / GRP;
      asrc[(size_t)gr * H + hd] = ps;
      adst[(size_t)gr * H + hd] = pd;
    }
  }
}

// ---------------- GAT aggregation: lane-parallel scores, single agg sweep ----

template <int H, bool RELU, bool LNPOOL>
__global__ __launch_bounds__(256) void gat_agg_kernel(
    const float* __restrict__ h, const float* __restrict__ asrc,
    const float* __restrict__ adst, const int* __restrict__ row_ptr,
    const int* __restrict__ col, const float* __restrict__ bias,
    const float* __restrict__ gamma, const float* __restrict__ beta,
    const int* __restrict__ batch, float* __restrict__ out, float* __restrict__ cnt,
    int n) {
  int node = (blockIdx.x * 256 + threadIdx.x) >> 6;
  int lane = threadIdx.x & 63;
  if (node >= n) return;
  int e0 = row_ptr[node];
  int ne = row_ptr[node + 1] - e0 + 1;  // incl. implicit self loop (last slot)

  float ad[H];
#pragma unroll
  for (int hh = 0; hh < H; ++hh) ad[hh] = adst[(size_t)node * H + hh];

  int c0 = lane * 2;
  const int hd = (H == 1) ? 0 : (c0 >> 5);  // 32 channels per head (H=4)

  float m[H], dpart[H];
#pragma unroll
  for (int hh = 0; hh < H; ++hh) { m[hh] = -1e30f; dpart[hh] = 0.f; }
  float2 acc = make_float2(0.f, 0.f);

#pragma unroll 1
  for (int base = 0; base < ne; base += 64) {
    int j = base + lane;
    bool valid = j < ne;
    int sj = node;  // self loop default (slot ne-1)
    if (valid && j < ne - 1) sj = col[e0 + j];

    // per-lane alpha (leaky-relu'd) for all heads
    float aj[H];
    if (valid) {
      if constexpr (H == 4) {
        float4 av = *(const float4*)(asrc + (size_t)sj * 4);
        aj[0] = av.x + ad[0]; aj[1] = av.y + ad[1];
        aj[2] = av.z + ad[2]; aj[3] = av.w + ad[3];
      } else {
        aj[0] = asrc[sj] + ad[0];
      }
#pragma unroll
      for (int hh = 0; hh < H; ++hh) aj[hh] = (aj[hh] > 0.f) ? aj[hh] : NEG_SLOPE * aj[hh];
    } else {
#pragma unroll
      for (int hh = 0; hh < H; ++hh) aj[hh] = -1e30f;
    }

    // chunk max per head (wave reduce)
    float cm[H];
#pragma unroll
    for (int hh = 0; hh < H; ++hh) cm[hh] = aj[hh];
#pragma unroll
    for (int off = 1; off < 64; off <<= 1) {
#pragma unroll
      for (int hh = 0; hh < H; ++hh) cm[hh] = fmaxf(cm[hh], __shfl_xor(cm[hh], off, 64));
    }

    if (base > 0) {  // online rescale (rare: deg > 63)
      float sc[H];
#pragma unroll
      for (int hh = 0; hh < H; ++hh) {
        float nm = fmaxf(m[hh], cm[hh]);
        sc[hh] = __expf(m[hh] - nm);
        m[hh] = nm;
        dpart[hh] *= sc[hh];
      }
      float sa = sc[0];
      if constexpr (H == 4) sa = (hd == 0) ? sc[0] : (hd == 1) ? sc[1] : (hd == 2) ? sc[2] : sc[3];
      acc.x *= sa; acc.y *= sa;
    } else {
#pragma unroll
      for (int hh = 0; hh < H; ++hh) m[hh] = cm[hh];
    }

    // per-lane exp + partial denom
    float ej[H];
#pragma unroll
    for (int hh = 0; hh < H; ++hh) {
      ej[hh] = valid ? __expf(aj[hh] - m[hh]) : 0.f;
      dpart[hh] += ej[hh];
    }

    // aggregate this chunk: serial over edges, full wave on channels;
    // loads are independent (coef comes from registers via shfl)
    int nc = (ne - base < 64) ? (ne - base) : 64;
#pragma unroll 1
    for (int t = 0; t < nc; ++t) {
      int s = __shfl(sj, t, 64);
      float ee;
      if constexpr (H == 4) {
        float g0 = __shfl(ej[0], t, 64);
        float g1 = __shfl(ej[1], t, 64);
        float g2 = __shfl(ej[2], t, 64);
        float g3 = __shfl(ej[3], t, 64);
        ee = (hd == 0) ? g0 : (hd == 1) ? g1 : (hd == 2) ? g2 : g3;
      } else {
        ee = __shfl(ej[0], t, 64);
      }
      float2 hv = *(const float2*)(h + (size_t)s * 128 + c0);
      acc.x = fmaf(hv.x, ee, acc.x);
      acc.y = fmaf(hv.y, ee, acc.y);
    }
  }

  // final denom (reduce per-lane partials)
  float den[H];
#pragma unroll
  for (int hh = 0; hh < H; ++hh) {
    den[hh] = dpart[hh];
#pragma unroll
    for (int off = 1; off < 64; off <<= 1) den[hh] += __shfl_xor(den[hh], off, 64);
  }
  float dd = den[0];
  if constexpr (H == 4) dd = (hd == 0) ? den[0] : (hd == 1) ? den[1] : (hd == 2) ? den[2] : den[3];
  float inv_dd = 1.f / dd;
  acc.x *= inv_dd;
  acc.y *= inv_dd;

  acc.x += bias[c0];
  acc.y += bias[c0 + 1];
  if (RELU) {
    acc.x = fmaxf(acc.x, 0.f);
    acc.y = fmaxf(acc.y, 0.f);
  }
  if (!LNPOOL) {
    *(float2*)(out + (size_t)node * 128 + c0) = acc;
  } else {
    float ssum = acc.x + acc.y;
#pragma unroll
    for (int off = 1; off < 64; off <<= 1) ssum += __shfl_xor(ssum, off, 64);
    float mu = ssum * (1.f / 128.f);
    float dx = acc.x - mu, dy = acc.y - mu;
    float vs2 = dx * dx + dy * dy;
#pragma unroll
    for (int off = 1; off < 64; off <<= 1) vs2 += __shfl_xor(vs2, off, 64);
    float inv = rsqrtf(vs2 * (1.f / 128.f) + LN_EPS);
    float ox = dx * inv * gamma[c0] + beta[c0];
    float oy = dy * inv * gamma[c0 + 1] + beta[c0 + 1];
    int g = batch[node];
    atomicAdd(&out[(size_t)g * 128 + c0], ox);
    atomicAdd(&out[(size_t)g * 128 + c0 + 1], oy);
    if (lane == 0) atomicAdd(&cnt[g], 1.0f);
  }
}

__global__ __launch_bounds__(256) void pool_div_kernel(float* __restrict__ out,
                                                       const float* __restrict__ cnt,
                                                       int total) {
  int i = blockIdx.x * 256 + threadIdx.x;
  if (i < total) out[i] = out[i] / fmaxf(cnt[i >> 7], 1.0f);
}

// ---------------- launch ----------------

extern "C" void kernel_launch(void* const* d_in, const int* in_sizes, int n_in,
                              void* d_out, int out_size, void* d_ws, size_t ws_size,
                              hipStream_t stream) {
  const float* x = (const float*)d_in[0];
  const int* ei = (const int*)d_in[1];
  const int* batch = (const int*)d_in[2];
  const float* W1 = (const float*)d_in[3];
  const float* att_src1 = (const float*)d_in[4];
  const float* att_dst1 = (const float*)d_in[5];
  const float* b1 = (const float*)d_in[6];
  const float* W2 = (const float*)d_in[7];
  const float* att_src2 = (const float*)d_in[8];
  const float* att_dst2 = (const float*)d_in[9];
  const float* b2 = (const float*)d_in[10];
  const float* gamma = (const float*)d_in[11];
  const float* beta = (const float*)d_in[12];
  float* out = (float*)d_out;

  const int N = N_NODES_C, E = N_EDGES_C, G = NUM_GRAPHS_C;
  const int* src = ei;
  const int* dst = ei + E;

  float* p = (float*)d_ws;
  float* h_a = p;   p += (size_t)N * 128;   // h1_pre, later h2_pre
  float* h_b = p;   p += (size_t)N * 128;   // h1 (post relu)
  float* asrc1 = p; p += (size_t)N * 4;
  float* adst1 = p; p += (size_t)N * 4;
  float* asrc2 = p; p += N;
  float* adst2 = p; p += N;
  float* cnt = p;   p += G;
  int* ip = (int*)p;
  int* deg = ip;     ip += N;
  int* cursor = ip;  ip += N;
  int* col = ip;     ip += E;
  int* bsums = ip;   ip += 256;
  int* bsums2 = ip;  ip += 256;
  int* row_ptr = ip; ip += N + 1;
  (void)ws_size; (void)in_sizes; (void)n_in; (void)out_size;

  hipMemsetAsync(deg, 0, sizeof(int) * (size_t)N, stream);
  hipMemsetAsync(cursor, 0, sizeof(int) * (size_t)N, stream);
  hipMemsetAsync(cnt, 0, sizeof(float) * (size_t)G, stream);
  hipMemsetAsync(d_out, 0, sizeof(float) * (size_t)G * 128, stream);

  // CSR by destination
  count_deg_kernel<<<(E + 255) / 256, 256, 0, stream>>>(dst, deg, E);
  int nblk = (N + 1023) / 1024;
  scan_kernel<<<nblk, 256, 0, stream>>>(deg, row_ptr, bsums, N);
  scan_kernel<<<1, 256, 0, stream>>>(bsums, bsums2, nullptr, nblk);
  scan_addoff_kernel<<<nblk, 256, 0, stream>>>(row_ptr, bsums2, N, E);
  fill_csr_kernel<<<(E + 255) / 256, 256, 0, stream>>>(src, dst, row_ptr, cursor, col, E);

  int wblocks = (int)(((size_t)N * 64 + 255) / 256);  // wave per node

  // Layer 1: GAT(128 -> 4x32), ReLU
  gemm_att<4><<<(N + 31) / 32, 256, 0, stream>>>(x, W1, att_src1, att_dst1, h_a, asrc1, adst1, N);
  gat_agg_kernel<4, true, false><<<wblocks, 256, 0, stream>>>(
      h_a, asrc1, adst1, row_ptr, col, b1, nullptr, nullptr, nullptr, h_b, nullptr, N);

  // Layer 2: GAT(128 -> 1x128) + LayerNorm + mean-pool (fused into epilogue)
  gemm_att<1><<<(N + 31) / 32, 256, 0, stream>>>(h_b, W2, att_src2, att_dst2, h_a, asrc2, adst2, N);
  gat_agg_kernel<1, false, true><<<wblocks, 256, 0, stream>>>(
      h_a, asrc2, adst2, row_ptr, col, b2, gamma, beta, batch, out, cnt, N);

  pool_div_kernel<<<(G * 128 + 255) / 256, 256, 0, stream>>>(out, cnt, G * 128);
}

// Round 4
// 664.982 us; speedup vs baseline: 10.6943x; 1.0035x over previous
//
#include <hip/hip_runtime.h>
#include <cstdint>
#include <cstddef>

#define N_NODES_C 200000
#define N_EDGES_C 600000
#define NUM_GRAPHS_C 20000

constexpr float NEG_SLOPE = 0.2f;
constexpr float LN_EPS = 1e-5f;

// ---------------- CSR build ----------------

__global__ __launch_bounds__(256) void count_deg_kernel(const int* __restrict__ dst,
                                                        int* __restrict__ deg, int E) {
  int e = blockIdx.x * 256 + threadIdx.x;
  if (e < E) atomicAdd(&deg[dst[e]], 1);
}

// exclusive scan, 1024 elements per block (256 threads x 4)
__global__ __launch_bounds__(256) void scan_kernel(const int* __restrict__ in,
                                                   int* __restrict__ out,
                                                   int* __restrict__ bsums, int n) {
  __shared__ int ss[256];
  int t = threadIdx.x;
  int base = blockIdx.x * 1024 + t * 4;
  int v[4];
  int s = 0;
#pragma unroll
  for (int j = 0; j < 4; ++j) {
    v[j] = (base + j < n) ? in[base + j] : 0;
    s += v[j];
  }
  ss[t] = s;
  __syncthreads();
  for (int off = 1; off < 256; off <<= 1) {
    int x = (t >= off) ? ss[t - off] : 0;
    __syncthreads();
    ss[t] += x;
    __syncthreads();
  }
  int incl = ss[t];
  int excl = incl - s;
  if (bsums != nullptr && t == 255) bsums[blockIdx.x] = incl;
  int run = excl;
#pragma unroll
  for (int j = 0; j < 4; ++j) {
    if (base + j < n) out[base + j] = run;
    run += v[j];
  }
}

__global__ __launch_bounds__(256) void scan_addoff_kernel(int* __restrict__ data,
                                                          const int* __restrict__ boff,
                                                          int n, int total) {
  int base = blockIdx.x * 1024 + threadIdx.x * 4;
  int add = boff[blockIdx.x];
#pragma unroll
  for (int j = 0; j < 4; ++j) {
    if (base + j < n) data[base + j] += add;
  }
  if (blockIdx.x == 0 && threadIdx.x == 0) data[n] = total;
}

__global__ __launch_bounds__(256) void fill_csr_kernel(const int* __restrict__ src,
                                                       const int* __restrict__ dst,
                                                       const int* __restrict__ row_ptr,
                                                       int* __restrict__ cursor,
                                                       int* __restrict__ col, int E) {
  int e = blockIdx.x * 256 + threadIdx.x;
  if (e < E) {
    int d = dst[e];
    int p = atomicAdd(&cursor[d], 1);
    col[row_ptr[d] + p] = src[e];
  }
}

// ---------------- GEMM + att-score epilogue ----------------
// C[M,128] = A[M,128] @ W[128,128]; also asrc[r,h] = <C row slice, att_src>,
// adst likewise, computed from acc registers (saves re-reading C: 2x102MB).
// 32x128 block tile, 4 rows x 4 cols/thread, outer K loop pinned (no spill).

template <int H>
__global__ __launch_bounds__(256) void gemm_att(const float* __restrict__ A,
                                                const float* __restrict__ W,
                                                const float* __restrict__ att_src,
                                                const float* __restrict__ att_dst,
                                                float* __restrict__ C,
                                                float* __restrict__ asrc,
                                                float* __restrict__ adst, int M) {
  __shared__ float As[32][32];
  __shared__ float Ws[32][128];
  int tid = threadIdx.x;
  int tx = tid & 31;   // col group (4 cols)
  int ty = tid >> 5;   // 0..7
  int row0 = blockIdx.x * 32;
  float4 acc[4];
#pragma unroll
  for (int r = 0; r < 4; ++r) acc[r] = make_float4(0.f, 0.f, 0.f, 0.f);

#pragma unroll 1
  for (int k0 = 0; k0 < 128; k0 += 32) {
    {
      int r = tid >> 3;
      int c4 = tid & 7;
      int gr = row0 + r;
      float4 v = make_float4(0.f, 0.f, 0.f, 0.f);
      if (gr < M) v = *(const float4*)(A + (size_t)gr * 128 + k0 + c4 * 4);
      *(float4*)&As[r][c4 * 4] = v;
    }
#pragma unroll
    for (int i = 0; i < 4; ++i) {
      int idx = tid + i * 256;
      int r = idx >> 5;
      int c4 = idx & 31;
      *(float4*)&Ws[r][c4 * 4] = *(const float4*)(W + (size_t)(k0 + r) * 128 + c4 * 4);
    }
    __syncthreads();
#pragma unroll
    for (int kk = 0; kk < 32; ++kk) {
      float4 w = *(const float4*)&Ws[kk][tx * 4];
#pragma unroll
      for (int r = 0; r < 4; ++r) {
        float a = As[ty + r * 8][kk];
        acc[r].x = fmaf(a, w.x, acc[r].x);
        acc[r].y = fmaf(a, w.y, acc[r].y);
        acc[r].z = fmaf(a, w.z, acc[r].z);
        acc[r].w = fmaf(a, w.w, acc[r].w);
      }
    }
    __syncthreads();
  }

  float4 vs = *(const float4*)(att_src + tx * 4);
  float4 vd = *(const float4*)(att_dst + tx * 4);
  constexpr int GRP = 32 / H;  // lanes per head within the 32-col group
#pragma unroll
  for (int r = 0; r < 4; ++r) {
    int gr = row0 + ty + r * 8;
    if (gr < M) *(float4*)(C + (size_t)gr * 128 + tx * 4) = acc[r];
    float ps = acc[r].x * vs.x + acc[r].y * vs.y + acc[r].z * vs.z + acc[r].w * vs.w;
    float pd = acc[r].x * vd.x + acc[r].y * vd.y + acc[r].z * vd.z + acc[r].w * vd.w;
#pragma unroll
    for (int off = 1; off < GRP; off <<= 1) {
      ps += __shfl_xor(ps, off, 64);
      pd += __shfl_xor(pd, off, 64);
    }
    if ((tx & (GRP - 1)) == 0 && gr < M) {
      int hd = tx / GRP;
      asrc[(size_t)gr * H + hd] = ps;
      adst[(size_t)gr * H + hd] = pd;
    }
  }
}

// ---------------- GAT aggregation: lane-parallel scores, single agg sweep ----

template <int H, bool RELU, bool LNPOOL>
__global__ __launch_bounds__(256) void gat_agg_kernel(
    const float* __restrict__ h, const float* __restrict__ asrc,
    const float* __restrict__ adst, const int* __restrict__ row_ptr,
    const int* __restrict__ col, const float* __restrict__ bias,
    const float* __restrict__ gamma, const float* __restrict__ beta,
    const int* __restrict__ batch, float* __restrict__ out, float* __restrict__ cnt,
    int n) {
  int node = (blockIdx.x * 256 + threadIdx.x) >> 6;
  int lane = threadIdx.x & 63;
  if (node >= n) return;
  int e0 = row_ptr[node];
  int ne = row_ptr[node + 1] - e0 + 1;  // incl. implicit self loop (last slot)

  float ad[H];
#pragma unroll
  for (int hh = 0; hh < H; ++hh) ad[hh] = adst[(size_t)node * H + hh];

  int c0 = lane * 2;
  const int hd = (H == 1) ? 0 : (c0 >> 5);  // 32 channels per head (H=4)

  float m[H], dpart[H];
#pragma unroll
  for (int hh = 0; hh < H; ++hh) { m[hh] = -1e30f; dpart[hh] = 0.f; }
  float2 acc = make_float2(0.f, 0.f);

#pragma unroll 1
  for (int base = 0; base < ne; base += 64) {
    int j = base + lane;
    bool valid = j < ne;
    int sj = node;  // self loop default (slot ne-1)
    if (valid && j < ne - 1) sj = col[e0 + j];

    // per-lane alpha (leaky-relu'd) for all heads
    float aj[H];
    if (valid) {
      if constexpr (H == 4) {
        float4 av = *(const float4*)(asrc + (size_t)sj * 4);
        aj[0] = av.x + ad[0]; aj[1] = av.y + ad[1];
        aj[2] = av.z + ad[2]; aj[3] = av.w + ad[3];
      } else {
        aj[0] = asrc[sj] + ad[0];
      }
#pragma unroll
      for (int hh = 0; hh < H; ++hh) aj[hh] = (aj[hh] > 0.f) ? aj[hh] : NEG_SLOPE * aj[hh];
    } else {
#pragma unroll
      for (int hh = 0; hh < H; ++hh) aj[hh] = -1e30f;
    }

    // chunk max per head (wave reduce)
    float cm[H];
#pragma unroll
    for (int hh = 0; hh < H; ++hh) cm[hh] = aj[hh];
#pragma unroll
    for (int off = 1; off < 64; off <<= 1) {
#pragma unroll
      for (int hh = 0; hh < H; ++hh) cm[hh] = fmaxf(cm[hh], __shfl_xor(cm[hh], off, 64));
    }

    if (base > 0) {  // online rescale (rare: deg > 63)
      float sc[H];
#pragma unroll
      for (int hh = 0; hh < H; ++hh) {
        float nm = fmaxf(m[hh], cm[hh]);
        sc[hh] = __expf(m[hh] - nm);
        m[hh] = nm;
        dpart[hh] *= sc[hh];
      }
      float sa = sc[0];
      if constexpr (H == 4) sa = (hd == 0) ? sc[0] : (hd == 1) ? sc[1] : (hd == 2) ? sc[2] : sc[3];
      acc.x *= sa; acc.y *= sa;
    } else {
#pragma unroll
      for (int hh = 0; hh < H; ++hh) m[hh] = cm[hh];
    }

    // per-lane exp + partial denom
    float ej[H];
#pragma unroll
    for (int hh = 0; hh < H; ++hh) {
      ej[hh] = valid ? __expf(aj[hh] - m[hh]) : 0.f;
      dpart[hh] += ej[hh];
    }

    // aggregate this chunk: serial over edges, full wave on channels;
    // loads are independent (coef comes from registers via shfl)
    int nc = (ne - base < 64) ? (ne - base) : 64;
#pragma unroll 1
    for (int t = 0; t < nc; ++t) {
      int s = __shfl(sj, t, 64);
      float ee;
      if constexpr (H == 4) {
        float g0 = __shfl(ej[0], t, 64);
        float g1 = __shfl(ej[1], t, 64);
        float g2 = __shfl(ej[2], t, 64);
        float g3 = __shfl(ej[3], t, 64);
        ee = (hd == 0) ? g0 : (hd == 1) ? g1 : (hd == 2) ? g2 : g3;
      } else {
        ee = __shfl(ej[0], t, 64);
      }
      float2 hv = *(const float2*)(h + (size_t)s * 128 + c0);
      acc.x = fmaf(hv.x, ee, acc.x);
      acc.y = fmaf(hv.y, ee, acc.y);
    }
  }

  // final denom (reduce per-lane partials)
  float den[H];
#pragma unroll
  for (int hh = 0; hh < H; ++hh) {
    den[hh] = dpart[hh];
#pragma unroll
    for (int off = 1; off < 64; off <<= 1) den[hh] += __shfl_xor(den[hh], off, 64);
  }
  float dd = den[0];
  if constexpr (H == 4) dd = (hd == 0) ? den[0] : (hd == 1) ? den[1] : (hd == 2) ? den[2] : den[3];
  float inv_dd = 1.f / dd;
  acc.x *= inv_dd;
  acc.y *= inv_dd;

  acc.x += bias[c0];
  acc.y += bias[c0 + 1];
  if (RELU) {
    acc.x = fmaxf(acc.x, 0.f);
    acc.y = fmaxf(acc.y, 0.f);
  }
  if (!LNPOOL) {
    *(float2*)(out + (size_t)node * 128 + c0) = acc;
  } else {
    float ssum = acc.x + acc.y;
#pragma unroll
    for (int off = 1; off < 64; off <<= 1) ssum += __shfl_xor(ssum, off, 64);
    float mu = ssum * (1.f / 128.f);
    float dx = acc.x - mu, dy = acc.y - mu;
    float vs2 = dx * dx + dy * dy;
#pragma unroll
    for (int off = 1; off < 64; off <<= 1) vs2 += __shfl_xor(vs2, off, 64);
    float inv = rsqrtf(vs2 * (1.f / 128.f) + LN_EPS);
    float ox = dx * inv * gamma[c0] + beta[c0];
    float oy = dy * inv * gamma[c0 + 1] + beta[c0 + 1];
    int g = batch[node];
    atomicAdd(&out[(size_t)g * 128 + c0], ox);
    atomicAdd(&out[(size_t)g * 128 + c0 + 1], oy);
    if (lane == 0) atomicAdd(&cnt[g], 1.0f);
  }
}

__global__ __launch_bounds__(256) void pool_div_kernel(float* __restrict__ out,
                                                       const float* __restrict__ cnt,
                                                       int total) {
  int i = blockIdx.x * 256 + threadIdx.x;
  if (i < total) out[i] = out[i] / fmaxf(cnt[i >> 7], 1.0f);
}

// ---------------- launch ----------------

extern "C" void kernel_launch(void* const* d_in, const int* in_sizes, int n_in,
                              void* d_out, int out_size, void* d_ws, size_t ws_size,
                              hipStream_t stream) {
  const float* x = (const float*)d_in[0];
  const int* ei = (const int*)d_in[1];
  const int* batch = (const int*)d_in[2];
  const float* W1 = (const float*)d_in[3];
  const float* att_src1 = (const float*)d_in[4];
  const float* att_dst1 = (const float*)d_in[5];
  const float* b1 = (const float*)d_in[6];
  const float* W2 = (const float*)d_in[7];
  const float* att_src2 = (const float*)d_in[8];
  const float* att_dst2 = (const float*)d_in[9];
  const float* b2 = (const float*)d_in[10];
  const float* gamma = (const float*)d_in[11];
  const float* beta = (const float*)d_in[12];
  float* out = (float*)d_out;

  const int N = N_NODES_C, E = N_EDGES_C, G = NUM_GRAPHS_C;
  const int* src = ei;
  const int* dst = ei + E;

  float* p = (float*)d_ws;
  float* h_a = p;   p += (size_t)N * 128;   // h1_pre, later h2_pre
  float* h_b = p;   p += (size_t)N * 128;   // h1 (post relu)
  float* asrc1 = p; p += (size_t)N * 4;
  float* adst1 = p; p += (size_t)N * 4;
  float* asrc2 = p; p += N;
  float* adst2 = p; p += N;
  float* cnt = p;   p += G;
  int* ip = (int*)p;
  int* deg = ip;     ip += N;
  int* cursor = ip;  ip += N;
  int* col = ip;     ip += E;
  int* bsums = ip;   ip += 256;
  int* bsums2 = ip;  ip += 256;
  int* row_ptr = ip; ip += N + 1;
  (void)ws_size; (void)in_sizes; (void)n_in; (void)out_size;

  hipMemsetAsync(deg, 0, sizeof(int) * (size_t)N, stream);
  hipMemsetAsync(cursor, 0, sizeof(int) * (size_t)N, stream);
  hipMemsetAsync(cnt, 0, sizeof(float) * (size_t)G, stream);
  hipMemsetAsync(d_out, 0, sizeof(float) * (size_t)G * 128, stream);

  // CSR by destination
  count_deg_kernel<<<(E + 255) / 256, 256, 0, stream>>>(dst, deg, E);
  int nblk = (N + 1023) / 1024;
  scan_kernel<<<nblk, 256, 0, stream>>>(deg, row_ptr, bsums, N);
  scan_kernel<<<1, 256, 0, stream>>>(bsums, bsums2, nullptr, nblk);
  scan_addoff_kernel<<<nblk, 256, 0, stream>>>(row_ptr, bsums2, N, E);
  fill_csr_kernel<<<(E + 255) / 256, 256, 0, stream>>>(src, dst, row_ptr, cursor, col, E);

  int wblocks = (int)(((size_t)N * 64 + 255) / 256);  // wave per node

  // Layer 1: GAT(128 -> 4x32), ReLU
  gemm_att<4><<<(N + 31) / 32, 256, 0, stream>>>(x, W1, att_src1, att_dst1, h_a, asrc1, adst1, N);
  gat_agg_kernel<4, true, false><<<wblocks, 256, 0, stream>>>(
      h_a, asrc1, adst1, row_ptr, col, b1, nullptr, nullptr, nullptr, h_b, nullptr, N);

  // Layer 2: GAT(128 -> 1x128) + LayerNorm + mean-pool (fused into epilogue)
  gemm_att<1><<<(N + 31) / 32, 256, 0, stream>>>(h_b, W2, att_src2, att_dst2, h_a, asrc2, adst2, N);
  gat_agg_kernel<1, false, true><<<wblocks, 256, 0, stream>>>(
      h_a, asrc2, adst2, row_ptr, col, b2, gamma, beta, batch, out, cnt, N);

  pool_div_kernel<<<(G * 128 + 255) / 256, 256, 0, stream>>>(out, cnt, G * 128);
}